// Round 6
// baseline (1039.026 us; speedup 1.0000x reference)
//
#include <hip/hip_runtime.h>

// SSIM, fused separable-conv single pass, ONE dispatch.
// x,y: [16,3,512,512] f32; window: [3,1,11,11] f32 (separable Gaussian).
// Output: scalar mean SSIM (f32).
//
// R2 block-tile structure (proven exact, no spills) + three fixes:
//  - TH 16->8: LDS 40.9->23.5 KB -> 6 blocks/CU (occupancy 41%->~75%)
//  - final mean fused via 256 hashed f64 atomic slots + last-block counter
//    (kills the ~90us second-dispatch/launch gap)
//  - phase-H window indexed straight out of float4 regs (no 16-float copy)

#define IMG_H 512
#define IMG_W 512
#define NC    48            // 16 batches * 3 channels

constexpr int TW = 64;      // output tile width
constexpr int TH = 8;       // output tile height
constexpr int SW = 78;      // staged cols: image 64bx-8 .. 64bx+69
constexpr int SH = 18;      // staged rows: image 8by-5 .. 8by+12
constexpr int SS = 78;      // staged LDS stride (words)
constexpr int VW = 76;      // vv stride (multiple of 4 for b128 alignment)
constexpr int NBX = IMG_W / TW;              // 8
constexpr int NBY = IMG_H / TH;              // 64
constexpr int NBLK = NBX * NBY * NC;         // 24576
constexpr int NSLOT = 256;

__global__ __launch_bounds__(256, 4)
void ssim_fused(const float* __restrict__ x, const float* __restrict__ y,
                const float* __restrict__ w, double* __restrict__ slots,
                int* __restrict__ counter, float* __restrict__ out)
{
    __shared__ __align__(16) float sx[SH][SS];
    __shared__ __align__(16) float sy[SH][SS];
    __shared__ __align__(16) float vv[5][TH][VW];  // vmu1, vmu2, vxx, vyy, vxy
    __shared__ float wsum[4];
    __shared__ double dsum[4];
    __shared__ int s_old;

    const int tid = threadIdx.x;
    const int x0 = blockIdx.x * TW - 8;    // staged col 0 (mult of 4 vs image)
    const int y0 = blockIdx.y * TH - 5;    // staged row 0
    const float* __restrict__ xp = x + (size_t)blockIdx.z * (IMG_H * IMG_W);
    const float* __restrict__ yp = y + (size_t)blockIdx.z * (IMG_H * IMG_W);

    // 1D gaussian from window row 5: w2d[5][k] = g5*g[k], g5 = sqrt(w[60]).
    float g[11];
    {
        const float gi = 1.0f / sqrtf(w[60]);
        #pragma unroll
        for (int k = 0; k < 11; ++k) g[k] = w[55 + k] * gi;
    }

    // ---- Phase 1: stage x,y halo region into LDS (zero OOB = zero padding)
    for (int i = tid; i < SH * SW; i += 256) {
        const int r = i / SW;
        const int c = i - r * SW;
        const int gr = y0 + r, gc = x0 + c;
        const bool ok = (gr >= 0) & (gr < IMG_H) & (gc >= 0) & (gc < IMG_W);
        const size_t idx = (size_t)gr * IMG_W + gc;
        sx[r][c] = ok ? xp[idx] : 0.0f;
        sy[r][c] = ok ? yp[idx] : 0.0f;
    }
    __syncthreads();

    // ---- Phase V: vertical 11-tap conv of {x,y,xx,yy,xy} at staged col c+2,
    //      4-row register blocking. 76 cols x 2 row-groups = 152 tasks.
    if (tid < 152) {
        const int c  = tid % 76;
        const int r0 = (tid / 76) << 2;     // 0 or 4
        float xv[14], yv[14], xxv[14], yyv[14], xyv[14];
        #pragma unroll
        for (int k = 0; k < 14; ++k) {
            const float a = sx[r0 + k][c + 2];
            const float b = sy[r0 + k][c + 2];
            xv[k] = a; yv[k] = b;
            xxv[k] = a * a; yyv[k] = b * b; xyv[k] = a * b;
        }
        #pragma unroll
        for (int j = 0; j < 4; ++j) {
            float s0 = 0.f, s1 = 0.f, s2 = 0.f, s3 = 0.f, s4 = 0.f;
            #pragma unroll
            for (int k = 0; k < 11; ++k) {
                const float gk = g[k];
                s0 = fmaf(gk, xv[j + k],  s0);
                s1 = fmaf(gk, yv[j + k],  s1);
                s2 = fmaf(gk, xxv[j + k], s2);
                s3 = fmaf(gk, yyv[j + k], s3);
                s4 = fmaf(gk, xyv[j + k], s4);
            }
            vv[0][r0 + j][c] = s0;
            vv[1][r0 + j][c] = s1;
            vv[2][r0 + j][c] = s2;
            vv[3][r0 + j][c] = s3;
            vv[4][r0 + j][c] = s4;
        }
    }
    __syncthreads();

    // ---- Phase H: horizontal 11-tap conv + SSIM on waves 0-1 (128 threads:
    //      8 rows x 16 quad-groups). Output col j taps vv[r][j+1 .. j+11];
    //      quad j0 needs vv[j0+1..j0+14] within aligned [j0, j0+16).
    const float C1 = 1e-4f;   // 0.01^2
    const float C2 = 9e-4f;   // 0.03^2
    float lsum = 0.0f;

    if (tid < 128) {
        const int r  = tid >> 4;            // 0..7
        const int j0 = (tid & 15) << 2;     // 0,4,...,60

        float acc[5][4];
        #pragma unroll
        for (int q = 0; q < 5; ++q) {
            const float4* vp = (const float4*)(&vv[q][r][j0]);
            float4 W[4];
            W[0] = vp[0]; W[1] = vp[1]; W[2] = vp[2]; W[3] = vp[3];
            const float* win = (const float*)W;   // subregister indexing
            #pragma unroll
            for (int t = 0; t < 4; ++t) {
                float s = 0.f;
                #pragma unroll
                for (int k = 0; k < 11; ++k) s = fmaf(g[k], win[t + 1 + k], s);
                acc[q][t] = s;
            }
        }

        #pragma unroll
        for (int t = 0; t < 4; ++t) {
            const float m1 = acc[0][t], m2 = acc[1][t];
            const float m1s = m1 * m1, m2s = m2 * m2, m12 = m1 * m2;
            const float v1  = acc[2][t] - m1s;
            const float v2  = acc[3][t] - m2s;
            const float v12 = acc[4][t] - m12;
            const float num = (2.0f * m12 + C1) * (2.0f * v12 + C2);
            const float den = (m1s + m2s + C1) * (v1 + v2 + C2);
            lsum += num / den;
        }
    }

    // ---- Block reduction
    #pragma unroll
    for (int off = 32; off > 0; off >>= 1)
        lsum += __shfl_down(lsum, off, 64);
    if ((tid & 63) == 0) wsum[tid >> 6] = lsum;
    __syncthreads();

    // ---- One hashed-slot f64 atomic per block; last block folds 256 slots.
    if (tid == 0) {
        const int wid = blockIdx.x + NBX * (blockIdx.y + NBY * blockIdx.z);
        const double blk = (double)wsum[0] + (double)wsum[1]
                         + (double)wsum[2] + (double)wsum[3];
        __hip_atomic_fetch_add(&slots[wid & (NSLOT - 1)], blk,
                               __ATOMIC_RELEASE, __HIP_MEMORY_SCOPE_AGENT);
        s_old = __hip_atomic_fetch_add(counter, 1,
                                       __ATOMIC_ACQ_REL, __HIP_MEMORY_SCOPE_AGENT);
    }
    __syncthreads();

    if (s_old == NBLK - 1) {               // uniform across block
        double s = __hip_atomic_load(&slots[tid], __ATOMIC_ACQUIRE,
                                     __HIP_MEMORY_SCOPE_AGENT);
        #pragma unroll
        for (int off = 32; off > 0; off >>= 1)
            s += __shfl_down(s, off, 64);
        if ((tid & 63) == 0) dsum[tid >> 6] = s;
        __syncthreads();
        if (tid == 0)
            out[0] = (float)((dsum[0] + dsum[1] + dsum[2] + dsum[3])
                             / (double)((size_t)NC * IMG_H * IMG_W));
    }
}

extern "C" void kernel_launch(void* const* d_in, const int* in_sizes, int n_in,
                              void* d_out, int out_size, void* d_ws, size_t ws_size,
                              hipStream_t stream)
{
    const float* x = (const float*)d_in[0];
    const float* y = (const float*)d_in[1];
    const float* w = (const float*)d_in[2];

    int*    counter = (int*)d_ws;                      // offset 0
    double* slots   = (double*)((char*)d_ws + 64);     // 256 doubles

    hipMemsetAsync(d_ws, 0, 64 + NSLOT * sizeof(double), stream);

    dim3 grid(NBX, NBY, NC);    // (8, 64, 48) = 24576 blocks
    ssim_fused<<<grid, 256, 0, stream>>>(x, y, w, slots, counter, (float*)d_out);
}

// Round 7
// 391.604 us; speedup vs baseline: 2.6533x; 2.6533x over previous
//
#include <hip/hip_runtime.h>

// SSIM, fused separable-conv single pass, ONE dispatch.
// x,y: [16,3,512,512] f32; window: [3,1,11,11] f32 (separable Gaussian).
// Output: scalar mean SSIM (f32).
//
// R6 compute path (validated exact) + cheap completion machinery:
//  - R6 lesson: RELEASE/ACQ_REL agent atomics emit buffer_wbl2/buffer_inv on
//    non-coherent-L2 XCDs -> 24576 L2 flushes -> 1 ms of idle. All cross-block
//    sync is now RELAXED atomic RMWs (execute at device coherence point, no
//    cache maintenance). Ordering slot-add -> counter-add via one explicit
//    s_waitcnt vmcnt(0); last block re-reads slots with atomicAdd(slot, 0.0).

#define IMG_H 512
#define IMG_W 512
#define NC    48            // 16 batches * 3 channels

constexpr int TW = 64;      // output tile width
constexpr int TH = 8;       // output tile height
constexpr int SW = 78;      // staged cols: image 64bx-8 .. 64bx+69
constexpr int SH = 18;      // staged rows: image 8by-5 .. 8by+12
constexpr int SS = 78;      // staged LDS stride (words)
constexpr int VW = 76;      // vv stride (multiple of 4 for b128 alignment)
constexpr int NBX = IMG_W / TW;              // 8
constexpr int NBY = IMG_H / TH;              // 64
constexpr int NBLK = NBX * NBY * NC;         // 24576
constexpr int NSLOT = 256;

__global__ __launch_bounds__(256, 4)
void ssim_fused(const float* __restrict__ x, const float* __restrict__ y,
                const float* __restrict__ w, double* __restrict__ slots,
                int* __restrict__ counter, float* __restrict__ out)
{
    __shared__ __align__(16) float sx[SH][SS];
    __shared__ __align__(16) float sy[SH][SS];
    __shared__ __align__(16) float vv[5][TH][VW];  // vmu1, vmu2, vxx, vyy, vxy
    __shared__ float wsum[4];
    __shared__ double dsum[4];
    __shared__ int s_old;

    const int tid = threadIdx.x;
    const int x0 = blockIdx.x * TW - 8;    // staged col 0 (mult of 4 vs image)
    const int y0 = blockIdx.y * TH - 5;    // staged row 0
    const float* __restrict__ xp = x + (size_t)blockIdx.z * (IMG_H * IMG_W);
    const float* __restrict__ yp = y + (size_t)blockIdx.z * (IMG_H * IMG_W);

    // 1D gaussian from window row 5: w2d[5][k] = g5*g[k], g5 = sqrt(w[60]).
    float g[11];
    {
        const float gi = 1.0f / sqrtf(w[60]);
        #pragma unroll
        for (int k = 0; k < 11; ++k) g[k] = w[55 + k] * gi;
    }

    // ---- Phase 1: stage x,y halo region into LDS (zero OOB = zero padding)
    for (int i = tid; i < SH * SW; i += 256) {
        const int r = i / SW;
        const int c = i - r * SW;
        const int gr = y0 + r, gc = x0 + c;
        const bool ok = (gr >= 0) & (gr < IMG_H) & (gc >= 0) & (gc < IMG_W);
        const size_t idx = (size_t)gr * IMG_W + gc;
        sx[r][c] = ok ? xp[idx] : 0.0f;
        sy[r][c] = ok ? yp[idx] : 0.0f;
    }
    __syncthreads();

    // ---- Phase V: vertical 11-tap conv of {x,y,xx,yy,xy} at staged col c+2,
    //      4-row register blocking. 76 cols x 2 row-groups = 152 tasks.
    if (tid < 152) {
        const int c  = tid % 76;
        const int r0 = (tid / 76) << 2;     // 0 or 4
        float xv[14], yv[14], xxv[14], yyv[14], xyv[14];
        #pragma unroll
        for (int k = 0; k < 14; ++k) {
            const float a = sx[r0 + k][c + 2];
            const float b = sy[r0 + k][c + 2];
            xv[k] = a; yv[k] = b;
            xxv[k] = a * a; yyv[k] = b * b; xyv[k] = a * b;
        }
        #pragma unroll
        for (int j = 0; j < 4; ++j) {
            float s0 = 0.f, s1 = 0.f, s2 = 0.f, s3 = 0.f, s4 = 0.f;
            #pragma unroll
            for (int k = 0; k < 11; ++k) {
                const float gk = g[k];
                s0 = fmaf(gk, xv[j + k],  s0);
                s1 = fmaf(gk, yv[j + k],  s1);
                s2 = fmaf(gk, xxv[j + k], s2);
                s3 = fmaf(gk, yyv[j + k], s3);
                s4 = fmaf(gk, xyv[j + k], s4);
            }
            vv[0][r0 + j][c] = s0;
            vv[1][r0 + j][c] = s1;
            vv[2][r0 + j][c] = s2;
            vv[3][r0 + j][c] = s3;
            vv[4][r0 + j][c] = s4;
        }
    }
    __syncthreads();

    // ---- Phase H: horizontal 11-tap conv + SSIM on waves 0-1 (128 threads:
    //      8 rows x 16 quad-groups). Output col j taps vv[r][j+1 .. j+11];
    //      quad j0 needs vv[j0+1..j0+14] within aligned [j0, j0+16).
    const float C1 = 1e-4f;   // 0.01^2
    const float C2 = 9e-4f;   // 0.03^2
    float lsum = 0.0f;

    if (tid < 128) {
        const int r  = tid >> 4;            // 0..7
        const int j0 = (tid & 15) << 2;     // 0,4,...,60

        float acc[5][4];
        #pragma unroll
        for (int q = 0; q < 5; ++q) {
            const float4* vp = (const float4*)(&vv[q][r][j0]);
            float4 W[4];
            W[0] = vp[0]; W[1] = vp[1]; W[2] = vp[2]; W[3] = vp[3];
            const float* win = (const float*)W;   // subregister indexing
            #pragma unroll
            for (int t = 0; t < 4; ++t) {
                float s = 0.f;
                #pragma unroll
                for (int k = 0; k < 11; ++k) s = fmaf(g[k], win[t + 1 + k], s);
                acc[q][t] = s;
            }
        }

        #pragma unroll
        for (int t = 0; t < 4; ++t) {
            const float m1 = acc[0][t], m2 = acc[1][t];
            const float m1s = m1 * m1, m2s = m2 * m2, m12 = m1 * m2;
            const float v1  = acc[2][t] - m1s;
            const float v2  = acc[3][t] - m2s;
            const float v12 = acc[4][t] - m12;
            const float num = (2.0f * m12 + C1) * (2.0f * v12 + C2);
            const float den = (m1s + m2s + C1) * (v1 + v2 + C2);
            lsum += num / den;
        }
    }

    // ---- Block reduction
    #pragma unroll
    for (int off = 32; off > 0; off >>= 1)
        lsum += __shfl_down(lsum, off, 64);
    if ((tid & 63) == 0) wsum[tid >> 6] = lsum;
    __syncthreads();

    // ---- One hashed-slot RELAXED f64 atomic per block; last block folds the
    //      256 slots. No release/acquire fences (no L2 flush): atomic RMWs are
    //      coherent at the device coherence point; explicit waitcnt orders the
    //      slot-add ack before the counter-add.
    if (tid == 0) {
        const int wid = blockIdx.x + NBX * (blockIdx.y + NBY * blockIdx.z);
        const double blk = (double)wsum[0] + (double)wsum[1]
                         + (double)wsum[2] + (double)wsum[3];
        atomicAdd(&slots[wid & (NSLOT - 1)], blk);
        asm volatile("s_waitcnt vmcnt(0)" ::: "memory");
        s_old = atomicAdd(counter, 1);
    }
    __syncthreads();

    if (s_old == NBLK - 1) {               // uniform across block; s_old value
                                           // control-orders the reads below
        double s = atomicAdd(&slots[tid], 0.0);   // RMW read at coherence point
        #pragma unroll
        for (int off = 32; off > 0; off >>= 1)
            s += __shfl_down(s, off, 64);
        if ((tid & 63) == 0) dsum[tid >> 6] = s;
        __syncthreads();
        if (tid == 0)
            out[0] = (float)((dsum[0] + dsum[1] + dsum[2] + dsum[3])
                             / (double)((size_t)NC * IMG_H * IMG_W));
    }
}

extern "C" void kernel_launch(void* const* d_in, const int* in_sizes, int n_in,
                              void* d_out, int out_size, void* d_ws, size_t ws_size,
                              hipStream_t stream)
{
    const float* x = (const float*)d_in[0];
    const float* y = (const float*)d_in[1];
    const float* w = (const float*)d_in[2];

    int*    counter = (int*)d_ws;                      // offset 0
    double* slots   = (double*)((char*)d_ws + 64);     // 256 doubles

    hipMemsetAsync(d_ws, 0, 64 + NSLOT * sizeof(double), stream);

    dim3 grid(NBX, NBY, NC);    // (8, 64, 48) = 24576 blocks
    ssim_fused<<<grid, 256, 0, stream>>>(x, y, w, slots, counter, (float*)d_out);
}